// Round 1
// baseline (89.639 us; speedup 1.0000x reference)
//
#include <hip/hip_runtime.h>

// Problem constants (fixed by the reference)
#define CIN      256
#define COUT     256
#define HWD      56
#define LSP      3136      // 56*56
#define BB       4
#define KDIM     2304      // CIN*9
#define NT       36        // KDIM/64
#define BLTOT    12544     // BB*LSP

// ws layout (bytes):
//   [0      .. 1024)      scale      (256 f32)
//   [1024   .. 2048)      has_exc    (256 i32)   <- memset 0
//   [2048   .. 38912)     cnt        (9216 i32)  <- memset 0
//   [38912  .. 2398208)   exc        (9216*64 i32)
//   [2398208.. 4204544)   S          (451584 f32)   layout S[n*12544 + bl]
//   [4204544.. 4254720)   common     (12544 f32)
#define OFF_SCALE   0
#define OFF_HASEXC  1024
#define OFF_CNT     2048
#define OFF_EXC     38912
#define OFF_S       2398208
#define OFF_COMMON  4204544

// K1: per-output-channel scale = mean|w|, sign exceptions (s != +1).
// Weight flat index = c*2304 + k, k = cin*9 + kh*3 + kw.
__global__ __launch_bounds__(256)
void k_prep(const float* __restrict__ w, float* __restrict__ scale,
            int* __restrict__ has_exc, int* __restrict__ cnt, int* __restrict__ exc) {
    int c = blockIdx.x;
    int t = threadIdx.x;
    const float* wr = w + c * KDIM;
    float s = 0.f;
#pragma unroll
    for (int i = 0; i < 9; ++i) {
        int k = i * 256 + t;            // coalesced
        float v = wr[k];
        s += fabsf(v);
        int sg = (v > 0.f) - (v < 0.f); // sign
        if (sg != 1) {                  // exception: contributes (sg-1)*A = -mag*A
            int n = k >> 6;
            int ti = k & 63;
            int mag = 1 - sg;           // 1 (zero weight) or 2 (negative weight)
            int idx = atomicAdd(&cnt[c * NT + n], 1);
            exc[(c * NT + n) * 64 + idx] = ti | (mag << 8);
            atomicOr(&has_exc[c], 1);
        }
    }
    __shared__ float red[256];
    red[t] = s;
    __syncthreads();
#pragma unroll
    for (int off = 128; off > 0; off >>= 1) {
        if (t < off) red[t] += red[t + off];
        __syncthreads();
    }
    if (t == 0) scale[c] = red[0] * (1.f / (float)KDIM);
}

// K2: base tile sums S[n*12544 + bl] = sum_{t=0..63} A[b,l,64n+t]
// A[b,l,k] = x[b, k/9, oh-1+(k%9)/3, ow-1+(k%9)%3] (zero padded).
// blockIdx.y = n (so the c/r walk is wave-uniform scalar math).
__global__ __launch_bounds__(256)
void k_tilesum(const float* __restrict__ x, float* __restrict__ S) {
    int n = blockIdx.y;
    int bl = blockIdx.x * 256 + threadIdx.x;     // 0..12543
    int b = bl / LSP;
    int l = bl - b * LSP;
    int oh = l / HWD;
    int ow = l - oh * HWD;
    int ihb = oh - 1, iwb = ow - 1;

    int k0 = n * 64;
    int c = k0 / 9;
    int r = k0 - 9 * c;
    const float* xc = x + (size_t)(b * CIN + c) * LSP;

    float s = 0.f;
#pragma unroll
    for (int j = 0; j < 64; ++j) {
        int kh = (r >= 3) + (r >= 6);
        int kw = r - 3 * kh;
        int ih = ihb + kh;
        int iw = iwb + kw;
        float v = 0.f;
        if ((unsigned)ih < (unsigned)HWD && (unsigned)iw < (unsigned)HWD)
            v = xc[ih * HWD + iw];
        s += v;                          // t-ascending, matches K-loop order
        if (++r == 9) { r = 0; xc += LSP; }
    }
    S[n * BLTOT + bl] = s;
}

// K3: common path (no weight exceptions): quantize each tile sum, accumulate,
// 8-bit wraparound, *16.
__global__ __launch_bounds__(256)
void k_common(const float* __restrict__ S, float* __restrict__ common) {
    int bl = blockIdx.x * 256 + threadIdx.x;     // 0..12543
    int acc = 0;
#pragma unroll
    for (int n = 0; n < NT; ++n) {
        float ps = S[n * BLTOT + bl] * 0.0625f;          // /16
        ps = fminf(fmaxf(ps, -16.f), 15.f);              // clip to [Qn,Qp], 5-bit
        acc += (int)rintf(ps);                           // round half-even
    }
    int w8 = ((acc + 128) & 255) - 128;                  // OA: 8-bit wraparound
    common[bl] = (float)(w8 << 4);                       // *16
}

// K4: out[b,c,l] = value * scale[c]. Common path is a broadcast; channels with
// weight exceptions recompute acc with per-(c,n) corrections.
__global__ __launch_bounds__(256)
void k_out(const float* __restrict__ x, const float* __restrict__ S,
           const float* __restrict__ common, const float* __restrict__ scale,
           const int* __restrict__ has_exc, const int* __restrict__ cnt,
           const int* __restrict__ exc, float* __restrict__ out) {
    int gid = blockIdx.x * 256 + threadIdx.x;    // 802816 threads
    int o4 = gid * 4;                            // 4 consecutive outputs, same c
    int l = o4 % LSP;
    int t = o4 / LSP;                            // b*COUT + c
    int c = t & 255;
    int b = t >> 8;

    float4 v;
    if (!has_exc[c]) {
        v = *(const float4*)&common[b * LSP + l];
    } else {
        float vv[4];
#pragma unroll
        for (int q = 0; q < 4; ++q) {
            int ll = l + q;
            int oh = ll / HWD, ow = ll - (ll / HWD) * HWD;
            int acc = 0;
            for (int n = 0; n < NT; ++n) {
                float ps = S[n * BLTOT + b * LSP + ll];
                int ct = cnt[c * NT + n];
                for (int e = 0; e < ct; ++e) {
                    int pk = exc[(c * NT + n) * 64 + e];
                    int ti = pk & 63;
                    int mag = pk >> 8;
                    int k = n * 64 + ti;
                    int ci = k / 9;
                    int r = k - 9 * ci;
                    int kh = r / 3;
                    int kw = r - 3 * kh;
                    int ih = oh - 1 + kh, iw = ow - 1 + kw;
                    float a = 0.f;
                    if ((unsigned)ih < (unsigned)HWD && (unsigned)iw < (unsigned)HWD)
                        a = x[(size_t)((b * CIN + ci) * HWD + ih) * HWD + iw];
                    ps -= (float)mag * a;
                }
                ps *= 0.0625f;
                ps = fminf(fmaxf(ps, -16.f), 15.f);
                acc += (int)rintf(ps);
            }
            int w8 = ((acc + 128) & 255) - 128;
            vv[q] = (float)(w8 << 4);
        }
        v = make_float4(vv[0], vv[1], vv[2], vv[3]);
    }
    float sc = scale[c];
    v.x *= sc; v.y *= sc; v.z *= sc; v.w *= sc;
    *(float4*)&out[o4] = v;
}

extern "C" void kernel_launch(void* const* d_in, const int* in_sizes, int n_in,
                              void* d_out, int out_size, void* d_ws, size_t ws_size,
                              hipStream_t stream) {
    const float* x = (const float*)d_in[0];       // (4,256,56,56) f32
    const float* w = (const float*)d_in[1];       // (589824,1) f32
    float* out = (float*)d_out;                   // (4,256,56,56) f32

    char* ws = (char*)d_ws;
    float* scale   = (float*)(ws + OFF_SCALE);
    int*   has_exc = (int*)  (ws + OFF_HASEXC);
    int*   cnt     = (int*)  (ws + OFF_CNT);
    int*   exc     = (int*)  (ws + OFF_EXC);
    float* S       = (float*)(ws + OFF_S);
    float* common  = (float*)(ws + OFF_COMMON);

    // zero has_exc + cnt (ws is poisoned 0xAA before every timed launch)
    hipMemsetAsync(ws + OFF_HASEXC, 0, OFF_EXC - OFF_HASEXC, stream);

    k_prep<<<COUT, 256, 0, stream>>>(w, scale, has_exc, cnt, exc);
    k_tilesum<<<dim3(BLTOT / 256, NT), 256, 0, stream>>>(x, S);
    k_common<<<BLTOT / 256, 256, 0, stream>>>(S, common);
    k_out<<<(BB * COUT * LSP) / (4 * 256), 256, 0, stream>>>(
        x, S, common, scale, has_exc, cnt, exc, out);
}

// Round 3
// 86.047 us; speedup vs baseline: 1.0417x; 1.0417x over previous
//
#include <hip/hip_runtime.h>

// Problem constants (fixed by the reference)
#define CIN      256
#define COUT     256
#define HWD      56
#define LSP      3136      // 56*56
#define BB       4
#define KDIM     2304      // CIN*9
#define NT       36        // KDIM/64
#define BLTOT    12544     // BB*LSP
#define NBX      49        // BLTOT/256
#define NTSB     (NT*NBX)  // 1764 tile-sum blocks

// ws layout (bytes):
//   [0      .. 1024)      scale      (256 f32)
//   [1024   .. 2048)      has_exc    (256 i32)
//   [2048   .. 38912)     cnt        (9216 i32)
//   [38912  .. 2398208)   exc        (9216*64 i32)
//   [2398208.. 4204544)   S          (451584 f32)  layout S[n*12544 + bl]
//   [4204544.. 4254720)   common     (12544 f32)
#define OFF_SCALE   0
#define OFF_HASEXC  1024
#define OFF_CNT     2048
#define OFF_EXC     38912
#define OFF_S       2398208
#define OFF_COMMON  4204544

// D1: fused dispatch.
//  blocks [0, NTSB):      tile sums S[n*BLTOT + bl] = sum_{t<64} A[b,l,64n+t]
//                         (t-ascending adds; fmaf(0/1, x, s) keeps bit-exactness)
//  blocks [NTSB, +COUT):  per-cout scale = mean|w| + sign-exception lists,
//                         with self-zeroed cnt/has_exc (replaces memsetAsync)
__global__ __launch_bounds__(256)
void k_main(const float* __restrict__ x, const float* __restrict__ w,
            float* __restrict__ S, float* __restrict__ scale,
            int* __restrict__ has_exc, int* __restrict__ cnt,
            int* __restrict__ exc) {
    int id  = blockIdx.x;
    int tid = threadIdx.x;
    if (id < NTSB) {
        int n  = id / NBX;                       // uniform
        int bl = (id - n * NBX) * 256 + tid;     // 0..12543
        int b  = bl / LSP;
        int l  = bl - b * LSP;
        int oh = l / HWD;
        int ow = l - oh * HWD;

        // 9 stencil offsets (clamped) + 0/1 masks, hoisted out of the k-loop.
        // Statically indexed -> stays in VGPRs (no scratch).
        float m[9]; int off[9];
#pragma unroll
        for (int r = 0; r < 9; ++r) {
            int kh = r / 3, kw = r - 3 * (r / 3);      // compile-time
            int ih = oh - 1 + kh, iw = ow - 1 + kw;
            bool ok = ((unsigned)ih < (unsigned)HWD) & ((unsigned)iw < (unsigned)HWD);
            m[r]   = ok ? 1.f : 0.f;
            off[r] = ok ? (ih * HWD + iw) : 0;
        }

        int k0 = n * 64;
        int c0 = k0 / 9;              // uniform
        int r0 = k0 - 9 * c0;         // uniform, == (n*64) % 9
        const float* xc = x + (size_t)(b * CIN + c0) * LSP;

        float s = 0.f;
        // head: channel c0, r = r0..8  (uniform trip)
#pragma unroll
        for (int r = 0; r < 9; ++r)
            if (r >= r0) s = fmaf(m[r], xc[off[r]], s);
        xc += LSP;
        // 6 full channels, static r
#pragma unroll
        for (int cc = 0; cc < 6; ++cc) {
#pragma unroll
            for (int r = 0; r < 9; ++r) s = fmaf(m[r], xc[off[r]], s);
            xc += LSP;
        }
        if (r0 == 8) {
            // 64 = 1 + 54 + 9: a 7th full channel, no tail
#pragma unroll
            for (int r = 0; r < 9; ++r) s = fmaf(m[r], xc[off[r]], s);
        } else {
            // tail: channel c0+7, r = 0..r0
#pragma unroll
            for (int r = 0; r < 9; ++r)
                if (r <= r0) s = fmaf(m[r], xc[off[r]], s);
        }
        S[n * BLTOT + bl] = s;
    } else {
        int c = id - NTSB;
        // self-zero this block's slice (replaces hipMemsetAsync)
        if (tid < NT) cnt[c * NT + tid] = 0;
        if (tid == 0) has_exc[c] = 0;
        __syncthreads();

        const float* wr = w + c * KDIM;
        float s = 0.f;
#pragma unroll
        for (int i = 0; i < 9; ++i) {
            int k = i * 256 + tid;               // coalesced
            float v = wr[k];
            s += fabsf(v);
            int sg = (v > 0.f) - (v < 0.f);
            if (sg != 1) {                       // exception: contributes -mag*A
                int n  = k >> 6;
                int ti = k & 63;
                int mag = 1 - sg;                // 1 (zero w) or 2 (negative w)
                int idx = atomicAdd(&cnt[c * NT + n], 1);
                exc[(c * NT + n) * 64 + idx] = ti | (mag << 8);
                atomicOr(&has_exc[c], 1);
            }
        }
        __shared__ float red[256];
        red[tid] = s;
        __syncthreads();
#pragma unroll
        for (int o = 128; o > 0; o >>= 1) {
            if (tid < o) red[tid] += red[tid + o];
            __syncthreads();
        }
        if (tid == 0) scale[c] = red[0] * (1.f / (float)KDIM);
    }
}

// D2: quantize each tile sum, accumulate (n ascending), 8-bit wraparound, *16.
__global__ __launch_bounds__(256)
void k_common(const float* __restrict__ S, float* __restrict__ common) {
    int bl = blockIdx.x * 256 + threadIdx.x;
    int acc = 0;
#pragma unroll
    for (int n = 0; n < NT; ++n) {
        float ps = S[n * BLTOT + bl] * 0.0625f;          // /16
        ps = fminf(fmaxf(ps, -16.f), 15.f);              // clip to 5-bit [Qn,Qp]
        acc += (int)rintf(ps);                           // round half-even
    }
    int w8 = ((acc + 128) & 255) - 128;                  // OA wraparound
    common[bl] = (float)(w8 << 4);                       // *2^shift
}

// D3: out[b,c,l] = value * scale[c]; broadcast of common unless channel has
// weight-sign exceptions (then recompute with corrections; cold path).
__global__ __launch_bounds__(256)
void k_out(const float* __restrict__ x, const float* __restrict__ S,
           const float* __restrict__ common, const float* __restrict__ scale,
           const int* __restrict__ has_exc, const int* __restrict__ cnt,
           const int* __restrict__ exc, float* __restrict__ out) {
    int gid = blockIdx.x * 256 + threadIdx.x;
    int o4 = gid * 4;                 // 4 consecutive outputs, same c (3136%4==0)
    int l = o4 % LSP;
    int t = o4 / LSP;                 // b*COUT + c
    int c = t & 255;
    int b = t >> 8;

    float4 v;
    if (!has_exc[c]) {
        v = *(const float4*)&common[b * LSP + l];
    } else {
        float vv[4];
#pragma unroll
        for (int q = 0; q < 4; ++q) {
            int ll = l + q;
            int oh = ll / HWD, ow = ll - (ll / HWD) * HWD;
            int acc = 0;
            for (int n = 0; n < NT; ++n) {
                float ps = S[n * BLTOT + b * LSP + ll];
                int ct = cnt[c * NT + n];
                for (int e = 0; e < ct; ++e) {
                    int pk = exc[(c * NT + n) * 64 + e];
                    int ti = pk & 63;
                    int mag = pk >> 8;
                    int k = n * 64 + ti;
                    int ci = k / 9;
                    int r = k - 9 * ci;
                    int kh = r / 3;
                    int kw = r - 3 * kh;
                    int ih = oh - 1 + kh, iw = ow - 1 + kw;
                    float a = 0.f;
                    if ((unsigned)ih < (unsigned)HWD && (unsigned)iw < (unsigned)HWD)
                        a = x[(size_t)((b * CIN + ci) * HWD + ih) * HWD + iw];
                    ps -= (float)mag * a;
                }
                ps *= 0.0625f;
                ps = fminf(fmaxf(ps, -16.f), 15.f);
                acc += (int)rintf(ps);
            }
            int w8 = ((acc + 128) & 255) - 128;
            vv[q] = (float)(w8 << 4);
        }
        v = make_float4(vv[0], vv[1], vv[2], vv[3]);
    }
    float sc = scale[c];
    v.x *= sc; v.y *= sc; v.z *= sc; v.w *= sc;
    *(float4*)&out[o4] = v;
}

extern "C" void kernel_launch(void* const* d_in, const int* in_sizes, int n_in,
                              void* d_out, int out_size, void* d_ws, size_t ws_size,
                              hipStream_t stream) {
    const float* x = (const float*)d_in[0];       // (4,256,56,56) f32
    const float* w = (const float*)d_in[1];       // (589824,1) f32
    float* out = (float*)d_out;                   // (4,256,56,56) f32

    char* ws = (char*)d_ws;
    float* scale   = (float*)(ws + OFF_SCALE);
    int*   has_exc = (int*)  (ws + OFF_HASEXC);
    int*   cnt     = (int*)  (ws + OFF_CNT);
    int*   exc     = (int*)  (ws + OFF_EXC);
    float* S       = (float*)(ws + OFF_S);
    float* common  = (float*)(ws + OFF_COMMON);

    k_main<<<NTSB + COUT, 256, 0, stream>>>(x, w, S, scale, has_exc, cnt, exc);
    k_common<<<BLTOT / 256, 256, 0, stream>>>(S, common);
    k_out<<<(BB * COUT * LSP) / (4 * 256), 256, 0, stream>>>(
        x, S, common, scale, has_exc, cnt, exc, out);
}